// Round 5
// baseline (19268.761 us; speedup 1.0000x reference)
//
#include <hip/hip_runtime.h>
#include <hip/hip_bf16.h>
#include <math.h>

// Problem constants (B,S,E,H,T) = (32, 512, 300, 512, 9)
#define S_LEN 512
#define BATCH 32
#define HDIM  512
#define NTAG  9
#define M_ROWS (S_LEN * BATCH)      // 16384 rows, m = s*32 + b
#define GATES  4096                 // 2 dirs * 4 gates * 512

typedef __hip_bfloat16 bf16;
typedef unsigned long long ull;
typedef float f32x4 __attribute__((ext_vector_type(4)));
typedef float f32x16 __attribute__((ext_vector_type(16)));
typedef short bfrag8 __attribute__((ext_vector_type(8)));   // 8 bf16 = 4 VGPR

__device__ __forceinline__ float bf2f(short s) {
    unsigned u = ((unsigned)(unsigned short)s) << 16;
    return __builtin_bit_cast(float, u);
}
__device__ __forceinline__ short f2bf(float f) {
    __hip_bfloat16 h = __float2bfloat16(f);
    return __builtin_bit_cast(short, h);
}
// fast gate nonlinearities (v_exp + v_rcp); exact at saturation
__device__ __forceinline__ float fsig(float x) {
    return __builtin_amdgcn_rcpf(1.f + __expf(-x));
}
__device__ __forceinline__ float ftanh(float x) {
    return 1.f - 2.f * __builtin_amdgcn_rcpf(1.f + __expf(2.f * x));
}

// ============================================================================
// MFMA GEMM: xg(M x 4096) = A(M x K) * Bw(4096 x K)^T + bias1[n] + bias2[n]
// (unchanged — verified absmax 0)
// ============================================================================
template <int AMODE>
__global__ __launch_bounds__(256) void gemm_xg(const void* __restrict__ Ap,
                                               const float* __restrict__ Bw,
                                               int K, int KT,
                                               const float* __restrict__ bias1,
                                               const float* __restrict__ bias2,
                                               short* __restrict__ xg) {
    __shared__ char smem[32768];
    char* As = smem;
    char* Bs = smem + 16384;
    const int tid = threadIdx.x;
    const int bm = blockIdx.y * 128;
    const int bn = blockIdx.x * 128;
    const int l  = tid & 63;
    const int wv = tid >> 6;
    const int wr = wv >> 1, wc = wv & 1;

    f32x4 acc[4][4] = {};

    const int r_st  = tid >> 1;
    const int kh    = tid & 1;
    const int xorr  = (r_st & 7) << 4;

    for (int kt = 0; kt < KT; kt++) {
        const int k0 = kt * 64;
        if (AMODE == 0) {
            const float* A = (const float*)Ap;
            int mg = bm + r_st;
            const float* arow = A + ((size_t)(mg & 31) * S_LEN + (mg >> 5)) * 300;
#pragma unroll
            for (int u = 0; u < 8; u++) {
                int kk = k0 + kh * 32 + u * 4;
                float4 v = make_float4(0.f, 0.f, 0.f, 0.f);
                if (kk + 4 <= K) v = *(const float4*)(arow + kk);
                short4 sv = make_short4(f2bf(v.x), f2bf(v.y), f2bf(v.z), f2bf(v.w));
                *(short4*)(As + ((r_st * 128 + (kh * 64 + u * 8)) ^ xorr)) = sv;
            }
        } else {
            const short* A = (const short*)Ap;
            const short* arow = A + (size_t)(bm + r_st) * 1024;
#pragma unroll
            for (int u = 0; u < 4; u++) {
                int kk = k0 + kh * 32 + u * 8;
                bfrag8 v = *(const bfrag8*)(arow + kk);
                *(bfrag8*)(As + ((r_st * 128 + (kh * 64 + u * 16)) ^ xorr)) = v;
            }
        }
        {
            const float* brow = Bw + (size_t)(bn + r_st) * K;
#pragma unroll
            for (int u = 0; u < 8; u++) {
                int kk = k0 + kh * 32 + u * 4;
                float4 v = make_float4(0.f, 0.f, 0.f, 0.f);
                if (kk + 4 <= K) v = *(const float4*)(brow + kk);
                short4 sv = make_short4(f2bf(v.x), f2bf(v.y), f2bf(v.z), f2bf(v.w));
                *(short4*)(Bs + ((r_st * 128 + (kh * 64 + u * 8)) ^ xorr)) = sv;
            }
        }
        __syncthreads();
#pragma unroll
        for (int kf = 0; kf < 2; kf++) {
            bfrag8 af[4], bfr[4];
#pragma unroll
            for (int ms = 0; ms < 4; ms++) {
                int row = wr * 64 + ms * 16 + (l & 15);
                af[ms] = *(const bfrag8*)(As + ((row * 128 + kf * 64 + (l >> 4) * 16) ^ ((row & 7) << 4)));
            }
#pragma unroll
            for (int ns = 0; ns < 4; ns++) {
                int row = wc * 64 + ns * 16 + (l & 15);
                bfr[ns] = *(const bfrag8*)(Bs + ((row * 128 + kf * 64 + (l >> 4) * 16) ^ ((row & 7) << 4)));
            }
#pragma unroll
            for (int ms = 0; ms < 4; ms++)
#pragma unroll
                for (int ns = 0; ns < 4; ns++)
                    acc[ms][ns] = __builtin_amdgcn_mfma_f32_16x16x32_bf16(af[ms], bfr[ns], acc[ms][ns], 0, 0, 0);
        }
        __syncthreads();
    }
#pragma unroll
    for (int ns = 0; ns < 4; ns++) {
        int n = bn + wc * 64 + ns * 16 + (l & 15);
        float bsum = bias1[n] + bias2[n];
#pragma unroll
        for (int ms = 0; ms < 4; ms++) {
#pragma unroll
            for (int r = 0; r < 4; r++) {
                int m = bm + wr * 64 + ms * 16 + (l >> 4) * 4 + r;
                xg[(size_t)m * GATES + n] = f2bf(acc[ms][ns][r] + bsum);
            }
        }
    }
}

// ============================================================================
// Persistent bidirectional LSTM scan, v3: 16 wgs x 512 thr (8 waves).
// wg = dir*8 + p; wg owns j in [p*64, p*64+64) for all 4 gates.
// Changes vs v2:
//  - per-WAVE flags (64/dir): producer wave stores its h slice, waits own vmcnt,
//    lane0 releases flag -> no producer barrier on critical path.
//  - consumers load h fragments DIRECTLY from pub (L3 atomics) into registers;
//    k-slice ks depends only on producer p=ks>>2 -> pipelined wait/load/MFMA.
//  - Cb parity double-buffer -> single __syncthreads per step.
// MFMA 32x32x16 maps (verified r3/r4): A row=l&31, k=(l>>5)*8+i; B col=l&31 same k;
// C col=l&31(n), b=(r&3)+8*(r>>2)+4*(l>>5).
// ============================================================================
__global__ __launch_bounds__(512, 1) void lstm_scan(const short* __restrict__ xg,
                                                    const float* __restrict__ whh,
                                                    ull* __restrict__ pub,     // 2 slots * 2 dirs * 4096 ull
                                                    short* __restrict__ hseq,  // (s*32+b) x 1024
                                                    int* __restrict__ flags) { // 2 dirs * 64 waves
    const int wg  = blockIdx.x;
    const int dir = wg >> 3;
    const int p   = wg & 7;
    const int tid = threadIdx.x;
    const int wv  = tid >> 6;
    const int l   = tid & 63;
    const int g   = wv >> 1;            // gate 0..3
    const int jb  = (wv & 1) * 32;      // j subtile within wg
    const int qh  = l >> 5;
    const int col = l & 31;

    __shared__ float Cb[2][4][32][64];  // parity-double-buffered gate exchange

    // ---- recurrent weights -> registers (once) ----
    bfrag8 wf[32];
    {
        const int n_row = g * 512 + p * 64 + jb + col;
        const float* sp = whh + ((size_t)dir * 2048 + n_row) * 512;
#pragma unroll
        for (int ks = 0; ks < 32; ks++) {
            const float* q = sp + ks * 16 + qh * 8;
            bfrag8 v;
#pragma unroll
            for (int u = 0; u < 8; u++) v[u] = f2bf(q[u]);
            wf[ks] = v;
        }
    }

    const int bg = tid >> 4;
    const int jq = tid & 15;
    float c4[4] = {0.f, 0.f, 0.f, 0.f};

    short4 xr_cur[4], xr_nxt[4];
    {
        const int s0 = dir ? (S_LEN - 1) : 0;
        size_t xoff = ((size_t)s0 * BATCH + bg) * GATES + dir * 2048 + p * 64 + jq * 4;
#pragma unroll
        for (int g2 = 0; g2 < 4; g2++) xr_cur[g2] = *(const short4*)(xg + xoff + g2 * 512);
    }

    int* fbase = flags + dir * 64;
    const int myflag = dir * 64 + p * 8 + wv;

    for (int t = 0; t < S_LEN; t++) {
        const int s = dir ? (S_LEN - 1 - t) : t;
        // ---- prefetch xg for t+1 ----
        {
            const int tn = (t + 1 < S_LEN) ? t + 1 : t;
            const int sn = dir ? (S_LEN - 1 - tn) : tn;
            size_t xoff = ((size_t)sn * BATCH + bg) * GATES + dir * 2048 + p * 64 + jq * 4;
#pragma unroll
            for (int g2 = 0; g2 < 4; g2++) xr_nxt[g2] = *(const short4*)(xg + xoff + g2 * 512);
        }
        // ---- pipelined: wait producer group -> load frags -> MFMA ----
        const ull* src = pub + (size_t)((t & 1) * 2 + dir) * 4096;
        ull bal;
        {
            int v = __hip_atomic_load(fbase + l, __ATOMIC_RELAXED, __HIP_MEMORY_SCOPE_AGENT);
            bal = __ballot(v >= t);
        }
        f32x16 acc = {};
        bfrag8 fr[2][4];
#define WAITG(grp)                                                                     \
        {                                                                              \
            int guard = 0;                                                             \
            while (((bal >> ((grp) * 8)) & 0xFFull) != 0xFFull) {                      \
                int v = __hip_atomic_load(fbase + l, __ATOMIC_RELAXED,                 \
                                          __HIP_MEMORY_SCOPE_AGENT);                   \
                bal = __ballot(v >= t);                                                \
                if (++guard > (1 << 13)) break;                                        \
            }                                                                          \
        }
#define LOADG(grp, dstf)                                                               \
        {                                                                              \
            _Pragma("unroll")                                                          \
            for (int q = 0; q < 4; q++) {                                              \
                int ks = (grp) * 4 + q;                                                \
                int base = col * 128 + ks * 4 + qh * 2;                                \
                union { ull u[2]; bfrag8 f; } cv;                                      \
                cv.u[0] = __hip_atomic_load(src + base, __ATOMIC_RELAXED,              \
                                            __HIP_MEMORY_SCOPE_AGENT);                 \
                cv.u[1] = __hip_atomic_load(src + base + 1, __ATOMIC_RELAXED,          \
                                            __HIP_MEMORY_SCOPE_AGENT);                 \
                (dstf)[q] = cv.f;                                                      \
            }                                                                          \
        }
        WAITG(0); LOADG(0, fr[0]);
#pragma unroll
        for (int grp = 0; grp < 8; grp++) {
            if (grp < 7) { WAITG(grp + 1); LOADG(grp + 1, fr[(grp + 1) & 1]); }
#pragma unroll
            for (int q = 0; q < 4; q++)
                acc = __builtin_amdgcn_mfma_f32_32x32x16_bf16(fr[grp & 1][q], wf[grp * 4 + q],
                                                              acc, 0, 0, 0);
        }
#undef WAITG
#undef LOADG
        // ---- C exchange (parity buffer), one barrier ----
#pragma unroll
        for (int r = 0; r < 16; r++) {
            int brow = (r & 3) + 8 * (r >> 2) + 4 * qh;
            Cb[t & 1][g][brow][jb + col] = acc[r];
        }
        __syncthreads();
        // ---- gates / state update ----
        float hv[4];
        {
            const float (*C)[32][64] = Cb[t & 1];
            float xi[4] = {bf2f(xr_cur[0].x), bf2f(xr_cur[0].y), bf2f(xr_cur[0].z), bf2f(xr_cur[0].w)};
            float xf[4] = {bf2f(xr_cur[1].x), bf2f(xr_cur[1].y), bf2f(xr_cur[1].z), bf2f(xr_cur[1].w)};
            float xc[4] = {bf2f(xr_cur[2].x), bf2f(xr_cur[2].y), bf2f(xr_cur[2].z), bf2f(xr_cur[2].w)};
            float xo[4] = {bf2f(xr_cur[3].x), bf2f(xr_cur[3].y), bf2f(xr_cur[3].z), bf2f(xr_cur[3].w)};
#pragma unroll
            for (int q = 0; q < 4; q++) {
                int jl = jq * 4 + q;
                float gi = C[0][bg][jl] + xi[q];
                float gf = C[1][bg][jl] + xf[q];
                float gc = C[2][bg][jl] + xc[q];
                float go = C[3][bg][jl] + xo[q];
                float cc = fsig(gf) * c4[q] + fsig(gi) * ftanh(gc);
                c4[q] = cc;
                hv[q] = fsig(go) * ftanh(cc);
            }
        }
        // ---- publish h[t+1] + hseq, then per-wave flag ----
        {
            ull pk = (ull)(unsigned short)f2bf(hv[0]) |
                     ((ull)(unsigned short)f2bf(hv[1]) << 16) |
                     ((ull)(unsigned short)f2bf(hv[2]) << 32) |
                     ((ull)(unsigned short)f2bf(hv[3]) << 48);
            ull* dst = pub + (size_t)(((t + 1) & 1) * 2 + dir) * 4096 + bg * 128 + p * 16 + jq;
            __hip_atomic_store(dst, pk, __ATOMIC_RELAXED, __HIP_MEMORY_SCOPE_AGENT);
            ull* hd = (ull*)(hseq + ((size_t)s * BATCH + bg) * 1024 + dir * HDIM + p * 64 + jq * 4);
            __builtin_nontemporal_store(pk, hd);
        }
#pragma unroll
        for (int g2 = 0; g2 < 4; g2++) xr_cur[g2] = xr_nxt[g2];
        asm volatile("s_waitcnt vmcnt(0)" ::: "memory");   // wave's publishes are in L3
        if (l == 0)
            __hip_atomic_store(flags + myflag, t + 1, __ATOMIC_RELEASE,
                               __HIP_MEMORY_SCOPE_AGENT);
    }
}

// ---- emissions (B,S,T) = h1 (M_ROWS,1024) bf16 @ proj_w(9,1024)^T + proj_b ----
__global__ __launch_bounds__(256) void proj_kernel(const bf16* __restrict__ h1,
                                                   const float* __restrict__ pw,
                                                   const float* __restrict__ pb,
                                                   float* __restrict__ em) {
    __shared__ float wl[NTAG * 1024];
    __shared__ float bl[NTAG];
    for (int i = threadIdx.x; i < NTAG * 1024; i += 256) wl[i] = pw[i];
    if (threadIdx.x < NTAG) bl[threadIdx.x] = pb[threadIdx.x];
    __syncthreads();
    int m = blockIdx.x * 256 + threadIdx.x;
    int s = m >> 5, b = m & 31;
    const bf16* hr = h1 + (size_t)m * 1024;
    float acc[NTAG] = {};
    for (int k = 0; k < 1024; k += 8) {
        uint4 raw = *(const uint4*)(hr + k);
        const bf16* hv = (const bf16*)&raw;
        float hf[8];
#pragma unroll
        for (int u = 0; u < 8; u++) hf[u] = __bfloat162float(hv[u]);
#pragma unroll
        for (int tt = 0; tt < NTAG; tt++) {
            const float* wrow = &wl[tt * 1024 + k];
#pragma unroll
            for (int u = 0; u < 8; u++) acc[tt] += hf[u] * wrow[u];
        }
    }
#pragma unroll
    for (int tt = 0; tt < NTAG; tt++)
        em[((size_t)b * S_LEN + s) * NTAG + tt] = acc[tt] + bl[tt];
}

// ---- CRF NLL per batch element ----
__global__ __launch_bounds__(64) void crf_kernel(const float* __restrict__ em,
                                                 const int* __restrict__ tags,
                                                 const int* __restrict__ mask,
                                                 const float* __restrict__ trans,
                                                 const float* __restrict__ startv,
                                                 const float* __restrict__ endv,
                                                 float* __restrict__ out_b) {
    int b = blockIdx.x;
    int lane = threadIdx.x;
    const float* E = em + (size_t)b * S_LEN * NTAG;
    const int* tg = tags + (size_t)b * S_LEN;
    const int* mk = mask + (size_t)b * S_LEN;

    float np = 0.f;
    int msum = 0;
    for (int s = lane; s < S_LEN; s += 64) {
        msum += (mk[s] != 0);
        if (s >= 1) {
            float mf = (float)mk[s];
            int ts = tg[s], tp = tg[s - 1];
            np += (E[(size_t)s * NTAG + ts] + trans[tp * NTAG + ts]) * mf;
        }
    }
    for (int off = 32; off; off >>= 1) {
        np += __shfl_down(np, off);
        msum += __shfl_down(msum, off);
    }
    np = __shfl(np, 0);
    msum = __shfl(msum, 0);

    int j = lane;
    float tcol[NTAG];
    if (j < NTAG)
#pragma unroll
        for (int i = 0; i < NTAG; i++) tcol[i] = trans[i * NTAG + j];
    float alpha = (j < NTAG) ? (startv[j] + E[j]) : -1e30f;
    for (int s = 1; s < S_LEN; s++) {
        float av[NTAG];
#pragma unroll
        for (int i = 0; i < NTAG; i++) av[i] = __shfl(alpha, i);
        if (j < NTAG) {
            float m = -1e30f;
#pragma unroll
            for (int i = 0; i < NTAG; i++) m = fmaxf(m, av[i] + tcol[i]);
            float ss = 0.f;
#pragma unroll
            for (int i = 0; i < NTAG; i++) ss += __expf(av[i] + tcol[i] - m);
            float nxt = m + __logf(ss) + E[(size_t)s * NTAG + j];
            if (mk[s] != 0) alpha = nxt;
        }
    }
    float val = (j < NTAG) ? (alpha + endv[j]) : -1e30f;
    float m2 = -1e30f, vv;
#pragma unroll
    for (int i = 0; i < NTAG; i++) { vv = __shfl(val, i); m2 = fmaxf(m2, vv); }
    float s2 = 0.f;
#pragma unroll
    for (int i = 0; i < NTAG; i++) { vv = __shfl(val, i); s2 += __expf(vv - m2); }
    float denom = m2 + __logf(s2);
    if (lane == 0) {
        int t0 = tg[0];
        int last = msum - 1;
        if (last < 0) last = 0;
        int lt = tg[last];
        float num = startv[t0] + E[t0] + np + endv[lt];
        out_b[b] = num - denom;
    }
}

__global__ __launch_bounds__(64) void finalize(const float* __restrict__ out_b,
                                               float* __restrict__ out) {
    int lane = threadIdx.x;
    float v = (lane < BATCH) ? out_b[lane] : 0.f;
    for (int off = 32; off; off >>= 1) v += __shfl_down(v, off);
    if (lane == 0) out[0] = -v / (float)BATCH;
}

extern "C" void kernel_launch(void* const* d_in, const int* in_sizes, int n_in,
                              void* d_out, int out_size, void* d_ws, size_t ws_size,
                              hipStream_t stream) {
    const float* x      = (const float*)d_in[0];
    const int*   tags   = (const int*)d_in[1];
    const int*   mask   = (const int*)d_in[2];
    const float* w_ih0  = (const float*)d_in[3];   // (2,2048,300)
    const float* w_hh0  = (const float*)d_in[4];   // (2,2048,512)
    const float* b_ih0  = (const float*)d_in[5];
    const float* b_hh0  = (const float*)d_in[6];
    const float* w_ih1  = (const float*)d_in[7];   // (2,2048,1024)
    const float* w_hh1  = (const float*)d_in[8];
    const float* b_ih1  = (const float*)d_in[9];
    const float* b_hh1  = (const float*)d_in[10];
    const float* pw     = (const float*)d_in[11];
    const float* pb     = (const float*)d_in[12];
    const float* trans  = (const float*)d_in[13];
    const float* startv = (const float*)d_in[14];
    const float* endv   = (const float*)d_in[15];

    // ---- ws layout (bytes). Total ~168.5 MB. ----
    char* ws = (char*)d_ws;
    size_t off = 0;
    short* xg    = (short*)(ws + off); off += (size_t)M_ROWS * GATES * 2;   // 134,217,728
    short* hseq  = (short*)(ws + off); off += (size_t)M_ROWS * 1024 * 2;    //  33,554,432
    ull*   pub   = (ull*)(ws + off);   off += (size_t)2 * 2 * 4096 * 8;     //     131,072
    int*   flags = (int*)(ws + off);   off += 4096;                          //     128 used
    float* emis  = (float*)(ws + off); off += (size_t)BATCH * S_LEN * NTAG * 4; // 589,824
    float* outb  = (float*)(ws + off); off += 256;
    if (off > ws_size) return;

    const size_t sync_bytes = (size_t)2 * 2 * 4096 * 8 + 4096; // pub + flags (adjacent)

    // ---- layer 0 ----
    gemm_xg<0><<<dim3(32, 128), 256, 0, stream>>>(x, w_ih0, 300, 5, b_ih0, b_hh0, xg);
    hipMemsetAsync(pub, 0, sync_bytes, stream);
    lstm_scan<<<16, 512, 0, stream>>>(xg, w_hh0, pub, hseq, flags);

    // ---- layer 1 ----
    gemm_xg<1><<<dim3(32, 128), 256, 0, stream>>>(hseq, w_ih1, 1024, 16, b_ih1, b_hh1, xg);
    hipMemsetAsync(pub, 0, sync_bytes, stream);
    lstm_scan<<<16, 512, 0, stream>>>(xg, w_hh1, pub, hseq, flags);

    // ---- projection + CRF ----
    proj_kernel<<<M_ROWS / 256, 256, 0, stream>>>((const bf16*)hseq, pw, pb, emis);
    crf_kernel<<<BATCH, 64, 0, stream>>>(emis, tags, mask, trans, startv, endv, outb);
    finalize<<<1, 64, 0, stream>>>(outb, (float*)d_out);
}

// Round 6
// 6589.601 us; speedup vs baseline: 2.9241x; 2.9241x over previous
//
#include <hip/hip_runtime.h>
#include <hip/hip_bf16.h>
#include <math.h>

// Problem constants (B,S,E,H,T) = (32, 512, 300, 512, 9)
#define S_LEN 512
#define BATCH 32
#define HDIM  512
#define NTAG  9
#define M_ROWS (S_LEN * BATCH)      // 16384 rows, m = s*32 + b
#define GATES  4096                 // 2 dirs * 4 gates * 512

typedef __hip_bfloat16 bf16;
typedef unsigned long long ull;
typedef float f32x4 __attribute__((ext_vector_type(4)));
typedef float f32x16 __attribute__((ext_vector_type(16)));
typedef short bfrag8 __attribute__((ext_vector_type(8)));   // 8 bf16 = 4 VGPR

__device__ __forceinline__ float bf2f(short s) {
    unsigned u = ((unsigned)(unsigned short)s) << 16;
    return __builtin_bit_cast(float, u);
}
__device__ __forceinline__ short f2bf(float f) {
    __hip_bfloat16 h = __float2bfloat16(f);
    return __builtin_bit_cast(short, h);
}
// fast gate nonlinearities (validated absmax-0 in rounds 4/5)
__device__ __forceinline__ float fsig(float x) {
    return __builtin_amdgcn_rcpf(1.f + __expf(-x));
}
__device__ __forceinline__ float ftanh(float x) {
    return 1.f - 2.f * __builtin_amdgcn_rcpf(1.f + __expf(2.f * x));
}

// ============================================================================
// MFMA GEMM: xg(M x 4096) = A(M x K) * Bw(4096 x K)^T + bias1[n] + bias2[n]
// (unchanged — verified absmax 0)
// ============================================================================
template <int AMODE>
__global__ __launch_bounds__(256) void gemm_xg(const void* __restrict__ Ap,
                                               const float* __restrict__ Bw,
                                               int K, int KT,
                                               const float* __restrict__ bias1,
                                               const float* __restrict__ bias2,
                                               short* __restrict__ xg) {
    __shared__ char smem[32768];
    char* As = smem;
    char* Bs = smem + 16384;
    const int tid = threadIdx.x;
    const int bm = blockIdx.y * 128;
    const int bn = blockIdx.x * 128;
    const int l  = tid & 63;
    const int wv = tid >> 6;
    const int wr = wv >> 1, wc = wv & 1;

    f32x4 acc[4][4] = {};

    const int r_st  = tid >> 1;
    const int kh    = tid & 1;
    const int xorr  = (r_st & 7) << 4;

    for (int kt = 0; kt < KT; kt++) {
        const int k0 = kt * 64;
        if (AMODE == 0) {
            const float* A = (const float*)Ap;
            int mg = bm + r_st;
            const float* arow = A + ((size_t)(mg & 31) * S_LEN + (mg >> 5)) * 300;
#pragma unroll
            for (int u = 0; u < 8; u++) {
                int kk = k0 + kh * 32 + u * 4;
                float4 v = make_float4(0.f, 0.f, 0.f, 0.f);
                if (kk + 4 <= K) v = *(const float4*)(arow + kk);
                short4 sv = make_short4(f2bf(v.x), f2bf(v.y), f2bf(v.z), f2bf(v.w));
                *(short4*)(As + ((r_st * 128 + (kh * 64 + u * 8)) ^ xorr)) = sv;
            }
        } else {
            const short* A = (const short*)Ap;
            const short* arow = A + (size_t)(bm + r_st) * 1024;
#pragma unroll
            for (int u = 0; u < 4; u++) {
                int kk = k0 + kh * 32 + u * 8;
                bfrag8 v = *(const bfrag8*)(arow + kk);
                *(bfrag8*)(As + ((r_st * 128 + (kh * 64 + u * 16)) ^ xorr)) = v;
            }
        }
        {
            const float* brow = Bw + (size_t)(bn + r_st) * K;
#pragma unroll
            for (int u = 0; u < 8; u++) {
                int kk = k0 + kh * 32 + u * 4;
                float4 v = make_float4(0.f, 0.f, 0.f, 0.f);
                if (kk + 4 <= K) v = *(const float4*)(brow + kk);
                short4 sv = make_short4(f2bf(v.x), f2bf(v.y), f2bf(v.z), f2bf(v.w));
                *(short4*)(Bs + ((r_st * 128 + (kh * 64 + u * 8)) ^ xorr)) = sv;
            }
        }
        __syncthreads();
#pragma unroll
        for (int kf = 0; kf < 2; kf++) {
            bfrag8 af[4], bfr[4];
#pragma unroll
            for (int ms = 0; ms < 4; ms++) {
                int row = wr * 64 + ms * 16 + (l & 15);
                af[ms] = *(const bfrag8*)(As + ((row * 128 + kf * 64 + (l >> 4) * 16) ^ ((row & 7) << 4)));
            }
#pragma unroll
            for (int ns = 0; ns < 4; ns++) {
                int row = wc * 64 + ns * 16 + (l & 15);
                bfr[ns] = *(const bfrag8*)(Bs + ((row * 128 + kf * 64 + (l >> 4) * 16) ^ ((row & 7) << 4)));
            }
#pragma unroll
            for (int ms = 0; ms < 4; ms++)
#pragma unroll
                for (int ns = 0; ns < 4; ns++)
                    acc[ms][ns] = __builtin_amdgcn_mfma_f32_16x16x32_bf16(af[ms], bfr[ns], acc[ms][ns], 0, 0, 0);
        }
        __syncthreads();
    }
#pragma unroll
    for (int ns = 0; ns < 4; ns++) {
        int n = bn + wc * 64 + ns * 16 + (l & 15);
        float bsum = bias1[n] + bias2[n];
#pragma unroll
        for (int ms = 0; ms < 4; ms++) {
#pragma unroll
            for (int r = 0; r < 4; r++) {
                int m = bm + wr * 64 + ms * 16 + (l >> 4) * 4 + r;
                xg[(size_t)m * GATES + n] = f2bf(acc[ms][ns][r] + bsum);
            }
        }
    }
}

// ============================================================================
// Persistent bidirectional LSTM scan, v4 = v2 structure + seqlock tag protocol.
// 16 wgs x 512 thr (8 waves). wg = dir*8 + p; wg owns j in [p*64, p*64+64), all gates.
// pub word (8B, atomic): [tag:32 | h(2k):16 | h(2k+1):16]; slot parity by step.
// Consumer polls its 16 words until all tags == t (memset-0 gives step-0 h=0),
// unpacks into swizzled LDS, 2 barriers/step, no flags, no producer vmcnt drain.
// MFMA 32x32x16 maps (verified r3/r4): A row=l&31, k=(l>>5)*8+i; B col=l&31 same k;
// C col=l&31(n), b=(r&3)+8*(r>>2)+4*(l>>5).
// ============================================================================
__global__ __launch_bounds__(512, 1) void lstm_scan(const short* __restrict__ xg,
                                                    const float* __restrict__ whh,
                                                    ull* __restrict__ pub,     // 2 slots * 2 dirs * 8192 words
                                                    short* __restrict__ hseq) {
    const int wg  = blockIdx.x;
    const int dir = wg >> 3;
    const int p   = wg & 7;
    const int tid = threadIdx.x;
    const int wv  = tid >> 6;
    const int l   = tid & 63;
    const int g   = wv >> 1;            // gate 0..3
    const int jb  = (wv & 1) * 32;      // j subtile within wg
    const int qh  = l >> 5;
    const int col = l & 31;

    __shared__ char hst[32768];         // h staged [32 b][1024 B], XOR-swizzled
    __shared__ float Cb[4][32][64];     // gate exchange

    // ---- recurrent weights -> registers (once); v2 loop shape ----
    bfrag8 wf[32];
    {
        const int n_row = g * 512 + p * 64 + jb + col;
        const float* sp = whh + ((size_t)dir * 2048 + n_row) * 512;
#pragma unroll
        for (int ks = 0; ks < 32; ks++) {
            const float* q = sp + ks * 16 + qh * 8;
            bfrag8 v;
#pragma unroll
            for (int u = 0; u < 8; u++) v[u] = f2bf(q[u]);
            wf[ks] = v;
        }
    }

    const int bg = tid >> 4;
    const int jq = tid & 15;
    float c4[4] = {0.f, 0.f, 0.f, 0.f};

    short4 xr_cur[4], xr_nxt[4];
    {
        const int s0 = dir ? (S_LEN - 1) : 0;
        size_t xoff = ((size_t)s0 * BATCH + bg) * GATES + dir * 2048 + p * 64 + jq * 4;
#pragma unroll
        for (int g2 = 0; g2 < 4; g2++) xr_cur[g2] = *(const short4*)(xg + xoff + g2 * 512);
    }

    for (int t = 0; t < S_LEN; t++) {
        const int s = dir ? (S_LEN - 1 - t) : t;
        // ---- prefetch xg for t+1 (hides under poll) ----
        {
            const int tn = (t + 1 < S_LEN) ? t + 1 : t;
            const int sn = dir ? (S_LEN - 1 - tn) : tn;
            size_t xoff = ((size_t)sn * BATCH + bg) * GATES + dir * 2048 + p * 64 + jq * 4;
#pragma unroll
            for (int g2 = 0; g2 < 4; g2++) xr_nxt[g2] = *(const short4*)(xg + xoff + g2 * 512);
        }
        // ---- poll-gather: my 16 words until all carry tag==t ----
        const ull* src = pub + (size_t)((t & 1) * 2 + dir) * 8192;
        const unsigned expect = (unsigned)t;
        ull wvv[16];
        {
            int rounds = 0;
            bool ok;
            do {
                if (rounds++) __builtin_amdgcn_s_sleep(1);
                ok = true;
#pragma unroll
                for (int i = 0; i < 16; i++) {
                    wvv[i] = __hip_atomic_load(src + tid + i * 512, __ATOMIC_RELAXED,
                                               __HIP_MEMORY_SCOPE_AGENT);
                    ok &= ((unsigned)(wvv[i] >> 32) == expect);
                }
                if (rounds > (1 << 14)) break;
            } while (!__all(ok));
        }
        // ---- unpack -> swizzled LDS ----
#pragma unroll
        for (int i = 0; i < 16; i++) {
            int w = tid + i * 512;
            int b = w >> 8, kp = w & 255;
            *(unsigned*)(hst + ((b * 1024 + kp * 4) ^ ((b & 15) << 4))) = (unsigned)wvv[i];
        }
        __syncthreads();
        // ---- MFMA: C(32b x 32n) = h(32x512) * W^T  (v2 loop shape) ----
        f32x16 acc = {};
#pragma unroll
        for (int ks = 0; ks < 32; ks++) {
            int byte = col * 1024 + ks * 32 + qh * 16;
            const bfrag8 a = *(const bfrag8*)(hst + (byte ^ ((col & 15) << 4)));
            acc = __builtin_amdgcn_mfma_f32_32x32x16_bf16(a, wf[ks], acc, 0, 0, 0);
        }
        // ---- C exchange ----
#pragma unroll
        for (int r = 0; r < 16; r++) {
            int brow = (r & 3) + 8 * (r >> 2) + 4 * qh;
            Cb[g][brow][jb + col] = acc[r];
        }
        __syncthreads();
        // ---- gates / state update ----
        float hv[4];
        {
            float xi[4] = {bf2f(xr_cur[0].x), bf2f(xr_cur[0].y), bf2f(xr_cur[0].z), bf2f(xr_cur[0].w)};
            float xf[4] = {bf2f(xr_cur[1].x), bf2f(xr_cur[1].y), bf2f(xr_cur[1].z), bf2f(xr_cur[1].w)};
            float xc[4] = {bf2f(xr_cur[2].x), bf2f(xr_cur[2].y), bf2f(xr_cur[2].z), bf2f(xr_cur[2].w)};
            float xo[4] = {bf2f(xr_cur[3].x), bf2f(xr_cur[3].y), bf2f(xr_cur[3].z), bf2f(xr_cur[3].w)};
#pragma unroll
            for (int q = 0; q < 4; q++) {
                int jl = jq * 4 + q;
                float gi = Cb[0][bg][jl] + xi[q];
                float gf = Cb[1][bg][jl] + xf[q];
                float gc = Cb[2][bg][jl] + xc[q];
                float go = Cb[3][bg][jl] + xo[q];
                float cc = fsig(gf) * c4[q] + fsig(gi) * ftanh(gc);
                c4[q] = cc;
                hv[q] = fsig(go) * ftanh(cc);
            }
        }
        // ---- publish h[t+1] as tagged words + hseq store (fire-and-forget) ----
        {
            unsigned short h0 = (unsigned short)f2bf(hv[0]);
            unsigned short h1 = (unsigned short)f2bf(hv[1]);
            unsigned short h2 = (unsigned short)f2bf(hv[2]);
            unsigned short h3 = (unsigned short)f2bf(hv[3]);
            ull tagw = (ull)(unsigned)(t + 1) << 32;
            ull w0 = tagw | (ull)h0 | ((ull)h1 << 16);
            ull w1 = tagw | (ull)h2 | ((ull)h3 << 16);
            ull* dst = pub + (size_t)(((t + 1) & 1) * 2 + dir) * 8192 + bg * 256 + p * 32 + jq * 2;
            __hip_atomic_store(dst, w0, __ATOMIC_RELAXED, __HIP_MEMORY_SCOPE_AGENT);
            __hip_atomic_store(dst + 1, w1, __ATOMIC_RELAXED, __HIP_MEMORY_SCOPE_AGENT);
            ull pk = (ull)h0 | ((ull)h1 << 16) | ((ull)h2 << 32) | ((ull)h3 << 48);
            ull* hd = (ull*)(hseq + ((size_t)s * BATCH + bg) * 1024 + dir * HDIM + p * 64 + jq * 4);
            __builtin_nontemporal_store(pk, hd);
        }
#pragma unroll
        for (int g2 = 0; g2 < 4; g2++) xr_cur[g2] = xr_nxt[g2];
    }
}

// ---- emissions (B,S,T) = h1 (M_ROWS,1024) bf16 @ proj_w(9,1024)^T + proj_b ----
__global__ __launch_bounds__(256) void proj_kernel(const bf16* __restrict__ h1,
                                                   const float* __restrict__ pw,
                                                   const float* __restrict__ pb,
                                                   float* __restrict__ em) {
    __shared__ float wl[NTAG * 1024];
    __shared__ float bl[NTAG];
    for (int i = threadIdx.x; i < NTAG * 1024; i += 256) wl[i] = pw[i];
    if (threadIdx.x < NTAG) bl[threadIdx.x] = pb[threadIdx.x];
    __syncthreads();
    int m = blockIdx.x * 256 + threadIdx.x;
    int s = m >> 5, b = m & 31;
    const bf16* hr = h1 + (size_t)m * 1024;
    float acc[NTAG] = {};
    for (int k = 0; k < 1024; k += 8) {
        uint4 raw = *(const uint4*)(hr + k);
        const bf16* hv = (const bf16*)&raw;
        float hf[8];
#pragma unroll
        for (int u = 0; u < 8; u++) hf[u] = __bfloat162float(hv[u]);
#pragma unroll
        for (int tt = 0; tt < NTAG; tt++) {
            const float* wrow = &wl[tt * 1024 + k];
#pragma unroll
            for (int u = 0; u < 8; u++) acc[tt] += hf[u] * wrow[u];
        }
    }
#pragma unroll
    for (int tt = 0; tt < NTAG; tt++)
        em[((size_t)b * S_LEN + s) * NTAG + tt] = acc[tt] + bl[tt];
}

// ---- CRF NLL per batch element ----
__global__ __launch_bounds__(64) void crf_kernel(const float* __restrict__ em,
                                                 const int* __restrict__ tags,
                                                 const int* __restrict__ mask,
                                                 const float* __restrict__ trans,
                                                 const float* __restrict__ startv,
                                                 const float* __restrict__ endv,
                                                 float* __restrict__ out_b) {
    int b = blockIdx.x;
    int lane = threadIdx.x;
    const float* E = em + (size_t)b * S_LEN * NTAG;
    const int* tg = tags + (size_t)b * S_LEN;
    const int* mk = mask + (size_t)b * S_LEN;

    float np = 0.f;
    int msum = 0;
    for (int s = lane; s < S_LEN; s += 64) {
        msum += (mk[s] != 0);
        if (s >= 1) {
            float mf = (float)mk[s];
            int ts = tg[s], tp = tg[s - 1];
            np += (E[(size_t)s * NTAG + ts] + trans[tp * NTAG + ts]) * mf;
        }
    }
    for (int off = 32; off; off >>= 1) {
        np += __shfl_down(np, off);
        msum += __shfl_down(msum, off);
    }
    np = __shfl(np, 0);
    msum = __shfl(msum, 0);

    int j = lane;
    float tcol[NTAG];
    if (j < NTAG)
#pragma unroll
        for (int i = 0; i < NTAG; i++) tcol[i] = trans[i * NTAG + j];
    float alpha = (j < NTAG) ? (startv[j] + E[j]) : -1e30f;
    for (int s = 1; s < S_LEN; s++) {
        float av[NTAG];
#pragma unroll
        for (int i = 0; i < NTAG; i++) av[i] = __shfl(alpha, i);
        if (j < NTAG) {
            float m = -1e30f;
#pragma unroll
            for (int i = 0; i < NTAG; i++) m = fmaxf(m, av[i] + tcol[i]);
            float ss = 0.f;
#pragma unroll
            for (int i = 0; i < NTAG; i++) ss += __expf(av[i] + tcol[i] - m);
            float nxt = m + __logf(ss) + E[(size_t)s * NTAG + j];
            if (mk[s] != 0) alpha = nxt;
        }
    }
    float val = (j < NTAG) ? (alpha + endv[j]) : -1e30f;
    float m2 = -1e30f, vv;
#pragma unroll
    for (int i = 0; i < NTAG; i++) { vv = __shfl(val, i); m2 = fmaxf(m2, vv); }
    float s2 = 0.f;
#pragma unroll
    for (int i = 0; i < NTAG; i++) { vv = __shfl(val, i); s2 += __expf(vv - m2); }
    float denom = m2 + __logf(s2);
    if (lane == 0) {
        int t0 = tg[0];
        int last = msum - 1;
        if (last < 0) last = 0;
        int lt = tg[last];
        float num = startv[t0] + E[t0] + np + endv[lt];
        out_b[b] = num - denom;
    }
}

__global__ __launch_bounds__(64) void finalize(const float* __restrict__ out_b,
                                               float* __restrict__ out) {
    int lane = threadIdx.x;
    float v = (lane < BATCH) ? out_b[lane] : 0.f;
    for (int off = 32; off; off >>= 1) v += __shfl_down(v, off);
    if (lane == 0) out[0] = -v / (float)BATCH;
}

extern "C" void kernel_launch(void* const* d_in, const int* in_sizes, int n_in,
                              void* d_out, int out_size, void* d_ws, size_t ws_size,
                              hipStream_t stream) {
    const float* x      = (const float*)d_in[0];
    const int*   tags   = (const int*)d_in[1];
    const int*   mask   = (const int*)d_in[2];
    const float* w_ih0  = (const float*)d_in[3];   // (2,2048,300)
    const float* w_hh0  = (const float*)d_in[4];   // (2,2048,512)
    const float* b_ih0  = (const float*)d_in[5];
    const float* b_hh0  = (const float*)d_in[6];
    const float* w_ih1  = (const float*)d_in[7];   // (2,2048,1024)
    const float* w_hh1  = (const float*)d_in[8];
    const float* b_ih1  = (const float*)d_in[9];
    const float* b_hh1  = (const float*)d_in[10];
    const float* pw     = (const float*)d_in[11];
    const float* pb     = (const float*)d_in[12];
    const float* trans  = (const float*)d_in[13];
    const float* startv = (const float*)d_in[14];
    const float* endv   = (const float*)d_in[15];

    // ---- ws layout (bytes). Total ~168.6 MB. ----
    char* ws = (char*)d_ws;
    size_t off = 0;
    short* xg    = (short*)(ws + off); off += (size_t)M_ROWS * GATES * 2;   // 134,217,728
    short* hseq  = (short*)(ws + off); off += (size_t)M_ROWS * 1024 * 2;    //  33,554,432
    ull*   pub   = (ull*)(ws + off);   off += (size_t)2 * 2 * 8192 * 8;     //     262,144
    float* emis  = (float*)(ws + off); off += (size_t)BATCH * S_LEN * NTAG * 4; // 589,824
    float* outb  = (float*)(ws + off); off += 256;
    if (off > ws_size) return;

    const size_t pub_bytes = (size_t)2 * 2 * 8192 * 8;

    // ---- layer 0 ----
    gemm_xg<0><<<dim3(32, 128), 256, 0, stream>>>(x, w_ih0, 300, 5, b_ih0, b_hh0, xg);
    hipMemsetAsync(pub, 0, pub_bytes, stream);
    lstm_scan<<<16, 512, 0, stream>>>(xg, w_hh0, pub, hseq);

    // ---- layer 1 ----
    gemm_xg<1><<<dim3(32, 128), 256, 0, stream>>>(hseq, w_ih1, 1024, 16, b_ih1, b_hh1, xg);
    hipMemsetAsync(pub, 0, pub_bytes, stream);
    lstm_scan<<<16, 512, 0, stream>>>(xg, w_hh1, pub, hseq);

    // ---- projection + CRF ----
    proj_kernel<<<M_ROWS / 256, 256, 0, stream>>>((const bf16*)hseq, pw, pb, emis);
    crf_kernel<<<BATCH, 64, 0, stream>>>(emis, tags, mask, trans, startv, endv, outb);
    finalize<<<1, 64, 0, stream>>>(outb, (float*)d_out);
}